// Round 1
// baseline (403.872 us; speedup 1.0000x reference)
//
#include <hip/hip_runtime.h>

// ---------------------------------------------------------------------------
// MultiHeadAttention forward, MI355X (gfx950), bf16 MFMA pipeline.
//   d_in: q(4096x1024 f32), k, v, mask(int32, ignored - causal known),
//         Wq, Wk, Wv, Wo (1024x1024 f32)
//   d_out: 4096x1024 f32
// Pipeline:
//   1) cast all fp32 inputs -> bf16 in ws
//   2) batched GEMM (z=3): Q=(q@WqT)->(h,s,d), K->(h,s,d), V->(h,d,s)
//   3) causal flash attention (16 heads, 64 q-rows/block, KVB=32) -> O bf16 (s, dm)
//   4) GEMM: out = O @ WoT -> fp32 d_out
// ---------------------------------------------------------------------------

typedef __attribute__((ext_vector_type(8))) short bf16x8;
typedef __attribute__((ext_vector_type(4))) float f32x4;

#define S_LEN 4096
#define DM 1024
#define NH 16
#define DH 64

static __device__ __forceinline__ unsigned short f2bf(float f) {
  union { float f; unsigned u; } x; x.f = f;
  unsigned u = x.u;
  u += 0x7fffu + ((u >> 16) & 1u);   // round-to-nearest-even
  return (unsigned short)(u >> 16);
}

// ---------------------------------------------------------------- cast kernel
struct CastArgs {
  const float* src[8];
  unsigned short* dst[8];
  int n[8];
};

__global__ __launch_bounds__(256) void cast_all(CastArgs a) {
  int which = blockIdx.y;
  const float* __restrict__ src = a.src[which];
  unsigned short* __restrict__ dst = a.dst[which];
  int n = a.n[which];
  int i = (blockIdx.x * 256 + threadIdx.x) * 8;
  if (i >= n) return;
  f32x4 v0 = *(const f32x4*)(src + i);
  f32x4 v1 = *(const f32x4*)(src + i + 4);
  union { bf16x8 v; unsigned short u[8]; } o;
#pragma unroll
  for (int j = 0; j < 4; j++) { o.u[j] = f2bf(v0[j]); o.u[4 + j] = f2bf(v1[j]); }
  *(bf16x8*)(dst + i) = o.v;
}

// ---------------------------------------------------------------- GEMM body
// C[M=4096][N=1024] = A[4096][1024] @ B[1024][1024]^T   (A,B bf16, B is N x K)
// 128x128 tile, BK=32, 4 waves, each wave 64x64 (4x4 16x16 frags).
// mode 0: fp32 C[s][n] -> Cout
// mode 1: bf16 (h, s, d) head layout   (n = h*64+d)
// mode 2: bf16 (h, d, s) transposed    (for V)
static __device__ __forceinline__ void gemm_body(
    const unsigned short* __restrict__ A, const unsigned short* __restrict__ B,
    void* __restrict__ Cout, int mode, unsigned short* As, unsigned short* Bs) {
  const int K = 1024;
  int tid = threadIdx.x;
  int wid = tid >> 6, lane = tid & 63;
  int m0 = blockIdx.y * 128, n0 = blockIdx.x * 128;
  int wr = (wid >> 1) * 64, wc = (wid & 1) * 64;
  int g = lane >> 4, r = lane & 15;

  // staging geometry: tile is 128 rows x 64B; wave w round rnd covers bytes
  // [w*1024 + rnd*4096 + lane*16, +16)
  int lin = wid * 1024 + lane * 16;
  int row0 = lin >> 6;
  int el0 = (lin & 63) >> 1;
  const unsigned short* gA0 = A + (size_t)(m0 + row0) * K + el0;
  const unsigned short* gA1 = gA0 + (size_t)64 * K;
  const unsigned short* gB0 = B + (size_t)(n0 + row0) * K + el0;
  const unsigned short* gB1 = gB0 + (size_t)64 * K;
  unsigned short* lA = As + wid * 512;   // wave-uniform LDS base
  unsigned short* lB = Bs + wid * 512;

  f32x4 acc[4][4] = {};

  for (int k0 = 0; k0 < K; k0 += 32) {
    __builtin_amdgcn_global_load_lds(
        (const __attribute__((address_space(1))) void*)(gA0 + k0),
        (__attribute__((address_space(3))) void*)lA, 16, 0, 0);
    __builtin_amdgcn_global_load_lds(
        (const __attribute__((address_space(1))) void*)(gA1 + k0),
        (__attribute__((address_space(3))) void*)(lA + 2048), 16, 0, 0);
    __builtin_amdgcn_global_load_lds(
        (const __attribute__((address_space(1))) void*)(gB0 + k0),
        (__attribute__((address_space(3))) void*)lB, 16, 0, 0);
    __builtin_amdgcn_global_load_lds(
        (const __attribute__((address_space(1))) void*)(gB1 + k0),
        (__attribute__((address_space(3))) void*)(lB + 2048), 16, 0, 0);
    __syncthreads();

    bf16x8 af[4], bfr[4];
#pragma unroll
    for (int mi = 0; mi < 4; mi++)
      af[mi] = *(const bf16x8*)&As[(wr + mi * 16 + r) * 32 + g * 8];
#pragma unroll
    for (int ni = 0; ni < 4; ni++)
      bfr[ni] = *(const bf16x8*)&Bs[(wc + ni * 16 + r) * 32 + g * 8];
#pragma unroll
    for (int mi = 0; mi < 4; mi++)
#pragma unroll
      for (int ni = 0; ni < 4; ni++)
        acc[mi][ni] = __builtin_amdgcn_mfma_f32_16x16x32_bf16(
            af[mi], bfr[ni], acc[mi][ni], 0, 0, 0);
    __syncthreads();
  }

  // epilogue: C frag layout col = lane&15, row = (lane>>4)*4 + reg  [m89/m91]
  if (mode == 0) {
    float* C = (float*)Cout;
#pragma unroll
    for (int mi = 0; mi < 4; mi++) {
      int row = m0 + wr + mi * 16 + g * 4;
#pragma unroll
      for (int ni = 0; ni < 4; ni++) {
        int c = n0 + wc + ni * 16 + r;
#pragma unroll
        for (int j = 0; j < 4; j++)
          C[(size_t)(row + j) * DM + c] = acc[mi][ni][j];
      }
    }
  } else if (mode == 1) {
    unsigned short* Cb = (unsigned short*)Cout;
#pragma unroll
    for (int mi = 0; mi < 4; mi++) {
      int row = m0 + wr + mi * 16 + g * 4;
#pragma unroll
      for (int ni = 0; ni < 4; ni++) {
        int c = n0 + wc + ni * 16 + r;
        int h = c >> 6, d = c & 63;
#pragma unroll
        for (int j = 0; j < 4; j++)
          Cb[(size_t)h * (S_LEN * DH) + (size_t)(row + j) * DH + d] =
              f2bf(acc[mi][ni][j]);
      }
    }
  } else {
    unsigned short* Cb = (unsigned short*)Cout;
#pragma unroll
    for (int mi = 0; mi < 4; mi++) {
      int row = m0 + wr + mi * 16 + g * 4;
#pragma unroll
      for (int ni = 0; ni < 4; ni++) {
        int c = n0 + wc + ni * 16 + r;
        int h = c >> 6, d = c & 63;
#pragma unroll
        for (int j = 0; j < 4; j++)
          Cb[(size_t)h * (S_LEN * DH) + (size_t)d * S_LEN + (row + j)] =
              f2bf(acc[mi][ni][j]);
      }
    }
  }
}

struct ProjArgs {
  const unsigned short* A[3];
  const unsigned short* B[3];
  unsigned short* C[3];
  int mode[3];
};

__global__ __launch_bounds__(256, 2) void gemm_proj(ProjArgs p) {
  __shared__ unsigned short As[4096];
  __shared__ unsigned short Bs[4096];
  int z = blockIdx.z;
  gemm_body(p.A[z], p.B[z], p.C[z], p.mode[z], As, Bs);
}

__global__ __launch_bounds__(256, 2) void gemm_one(
    const unsigned short* __restrict__ A, const unsigned short* __restrict__ B,
    void* __restrict__ Cout, int mode) {
  __shared__ unsigned short As[4096];
  __shared__ unsigned short Bs[4096];
  gemm_body(A, B, Cout, mode, As, Bs);
}

// ---------------------------------------------------------------- attention
// grid (64 qblocks, 16 heads), 256 threads. Each wave owns 16 q-rows.
// Qh,Kh: (h, s, d) bf16; Vt: (h, d, s) bf16; O: (s, dm) bf16.
__global__ __launch_bounds__(256, 2) void attn_fwd(
    const unsigned short* __restrict__ Qh, const unsigned short* __restrict__ Kh,
    const unsigned short* __restrict__ Vt, unsigned short* __restrict__ O) {
  __shared__ unsigned short Ks[32][72];    // 32 kv rows x 64 d (+8 pad)
  __shared__ unsigned short Vs[64][40];    // 64 d rows x 32 kv (+8 pad)
  __shared__ unsigned short Ps[4][16][40]; // per-wave P tile (+8 pad)

  int h = blockIdx.y, qb = blockIdx.x;
  int q0 = qb * 64;
  int tid = threadIdx.x, wid = tid >> 6, lane = tid & 63;
  int g = lane >> 4, r = lane & 15;
  int qw = q0 + wid * 16;

  const unsigned short* Qb = Qh + (size_t)h * (S_LEN * DH);
  const unsigned short* Kb = Kh + (size_t)h * (S_LEN * DH);
  const unsigned short* Vb = Vt + (size_t)h * (S_LEN * DH);

  // Q fragments (A operand): row = r (q), k(d) = g*8+j ; two 32-wide d chunks
  bf16x8 qf0 = *(const bf16x8*)&Qb[(size_t)(qw + r) * DH + g * 8];
  bf16x8 qf1 = *(const bf16x8*)&Qb[(size_t)(qw + r) * DH + 32 + g * 8];

  f32x4 oacc[4] = {};
  float m_r[4], l_r[4];
#pragma unroll
  for (int j = 0; j < 4; j++) { m_r[j] = -1e30f; l_r[j] = 0.f; }

  int sk_row = tid >> 3, sk_e = (tid & 7) * 8;   // K tile: 32 x 64
  int sv_row = tid >> 2, sv_e = (tid & 3) * 8;   // Vt tile: 64 x 32

  for (int kv0 = 0; kv0 < q0 + 64; kv0 += 32) {
    bf16x8 kv_ = *(const bf16x8*)&Kb[(size_t)(kv0 + sk_row) * DH + sk_e];
    *(bf16x8*)&Ks[sk_row][sk_e] = kv_;
    bf16x8 vv_ = *(const bf16x8*)&Vb[(size_t)sv_row * S_LEN + kv0 + sv_e];
    *(bf16x8*)&Vs[sv_row][sv_e] = vv_;
    __syncthreads();

    if (kv0 <= qw + 15) {  // wave-uniform: skip fully-masked tiles
      f32x4 s0 = {}, s1 = {};
      bf16x8 kf;
      kf = *(const bf16x8*)&Ks[r][g * 8];
      s0 = __builtin_amdgcn_mfma_f32_16x16x32_bf16(qf0, kf, s0, 0, 0, 0);
      kf = *(const bf16x8*)&Ks[r][32 + g * 8];
      s0 = __builtin_amdgcn_mfma_f32_16x16x32_bf16(qf1, kf, s0, 0, 0, 0);
      kf = *(const bf16x8*)&Ks[16 + r][g * 8];
      s1 = __builtin_amdgcn_mfma_f32_16x16x32_bf16(qf0, kf, s1, 0, 0, 0);
      kf = *(const bf16x8*)&Ks[16 + r][32 + g * 8];
      s1 = __builtin_amdgcn_mfma_f32_16x16x32_bf16(qf1, kf, s1, 0, 0, 0);

      // online softmax; S frag: row = qw + g*4 + j, col = kv0 + t*16 + r
      int qrow_b = qw + g * 4;
      int kc0 = kv0 + r, kc1 = kv0 + 16 + r;
      float sc[4], p0[4], p1[4];
#pragma unroll
      for (int j = 0; j < 4; j++) {
        float a = (kc0 <= qrow_b + j) ? s0[j] * 0.125f : -1e30f;
        float b = (kc1 <= qrow_b + j) ? s1[j] * 0.125f : -1e30f;
        float mx = fmaxf(a, b);
        mx = fmaxf(mx, __shfl_xor(mx, 1, 64));
        mx = fmaxf(mx, __shfl_xor(mx, 2, 64));
        mx = fmaxf(mx, __shfl_xor(mx, 4, 64));
        mx = fmaxf(mx, __shfl_xor(mx, 8, 64));
        float mnew = fmaxf(m_r[j], mx);
        sc[j] = __expf(m_r[j] - mnew);
        a = __expf(a - mnew);
        b = __expf(b - mnew);
        p0[j] = a; p1[j] = b;
        float rs = a + b;
        rs += __shfl_xor(rs, 1, 64);
        rs += __shfl_xor(rs, 2, 64);
        rs += __shfl_xor(rs, 4, 64);
        rs += __shfl_xor(rs, 8, 64);
        l_r[j] = l_r[j] * sc[j] + rs;
        m_r[j] = mnew;
      }
#pragma unroll
      for (int dt = 0; dt < 4; dt++)
#pragma unroll
        for (int j = 0; j < 4; j++) oacc[dt][j] *= sc[j];

      // P -> LDS (bf16), then read as PV A operand (in-order LDS within wave)
#pragma unroll
      for (int j = 0; j < 4; j++) {
        Ps[wid][g * 4 + j][r] = f2bf(p0[j]);
        Ps[wid][g * 4 + j][16 + r] = f2bf(p1[j]);
      }
      bf16x8 pa = *(const bf16x8*)&Ps[wid][r][g * 8];
#pragma unroll
      for (int dt = 0; dt < 4; dt++) {
        bf16x8 vf = *(const bf16x8*)&Vs[dt * 16 + r][g * 8];
        oacc[dt] = __builtin_amdgcn_mfma_f32_16x16x32_bf16(pa, vf, oacc[dt], 0, 0, 0);
      }
    }
    __syncthreads();
  }

  // epilogue: O[q][h*64 + d] = oacc / l
#pragma unroll
  for (int j = 0; j < 4; j++) {
    float rl = 1.0f / l_r[j];
    int row = qw + g * 4 + j;
#pragma unroll
    for (int dt = 0; dt < 4; dt++)
      O[(size_t)row * DM + h * DH + dt * 16 + r] = f2bf(oacc[dt][j] * rl);
  }
}

// ---------------------------------------------------------------- launch
extern "C" void kernel_launch(void* const* d_in, const int* in_sizes, int n_in,
                              void* d_out, int out_size, void* d_ws, size_t ws_size,
                              hipStream_t stream) {
  const float* q = (const float*)d_in[0];
  const float* k = (const float*)d_in[1];
  const float* v = (const float*)d_in[2];
  // d_in[3] = mask (causal, reconstructed analytically)
  const float* Wq = (const float*)d_in[4];
  const float* Wk = (const float*)d_in[5];
  const float* Wv = (const float*)d_in[6];
  const float* Wo = (const float*)d_in[7];

  unsigned short* W = (unsigned short*)d_ws;
  const int SM = S_LEN * DM;        // 4194304
  const int WM = DM * DM;           // 1048576
  unsigned short* qb  = W;
  unsigned short* kb  = qb + SM;
  unsigned short* vb  = kb + SM;
  unsigned short* Wqb = vb + SM;
  unsigned short* Wkb = Wqb + WM;
  unsigned short* Wvb = Wkb + WM;
  unsigned short* Wob = Wvb + WM;
  unsigned short* Qh  = Wob + WM;
  unsigned short* Kh  = Qh + SM;
  unsigned short* Vt  = Kh + SM;
  unsigned short* Ob  = Vt + SM;

  // 1) casts (fused, 8 arrays)
  CastArgs ca;
  ca.src[0] = q;  ca.dst[0] = qb;  ca.n[0] = SM;
  ca.src[1] = k;  ca.dst[1] = kb;  ca.n[1] = SM;
  ca.src[2] = v;  ca.dst[2] = vb;  ca.n[2] = SM;
  ca.src[3] = Wq; ca.dst[3] = Wqb; ca.n[3] = WM;
  ca.src[4] = Wk; ca.dst[4] = Wkb; ca.n[4] = WM;
  ca.src[5] = Wv; ca.dst[5] = Wvb; ca.n[5] = WM;
  ca.src[6] = Wo; ca.dst[6] = Wob; ca.n[6] = WM;
  ca.src[7] = Wo; ca.dst[7] = Wob; ca.n[7] = 0;   // unused slot
  cast_all<<<dim3(2048, 8), 256, 0, stream>>>(ca);

  // 2) batched projections
  ProjArgs pa;
  pa.A[0] = qb; pa.B[0] = Wqb; pa.C[0] = Qh; pa.mode[0] = 1;
  pa.A[1] = kb; pa.B[1] = Wkb; pa.C[1] = Kh; pa.mode[1] = 1;
  pa.A[2] = vb; pa.B[2] = Wvb; pa.C[2] = Vt; pa.mode[2] = 2;
  gemm_proj<<<dim3(8, 32, 3), 256, 0, stream>>>(pa);

  // 3) causal flash attention
  attn_fwd<<<dim3(64, 16), 256, 0, stream>>>(Qh, Kh, Vt, Ob);

  // 4) output projection -> fp32
  gemm_one<<<dim3(8, 32), 256, 0, stream>>>(Ob, Wob, d_out, 0);
}

// Round 2
// 195.387 us; speedup vs baseline: 2.0670x; 2.0670x over previous
//
#include <hip/hip_runtime.h>

// ---------------------------------------------------------------------------
// MultiHeadAttention forward, MI355X (gfx950), bf16 MFMA pipeline.
// Round 2: attention rewritten on swapped-operand 32x32 MFMA structure:
//   - mfma(K,Q) -> S^T: P-row lane-local, softmax reduce = tree + 1 shfl_xor(32)
//   - in-register P via v_cvt_pk_bf16_f32 + shfl_xor(32) (no P LDS)
//   - double-buffered K/V LDS, XOR-swizzled, reg-prefetch (T14)
//   - complementary causal work pairing across CU-resident blocks
//   - 1/sqrt(D_HEAD) folded into Wq cast
// ---------------------------------------------------------------------------

typedef __attribute__((ext_vector_type(8))) short bf16x8;
typedef __attribute__((ext_vector_type(4))) float f32x4;
typedef __attribute__((ext_vector_type(16))) float f32x16;

#define S_LEN 4096
#define DM 1024
#define NH 16
#define DH 64

static __device__ __forceinline__ unsigned short f2bf(float f) {
  union { float f; unsigned u; } x; x.f = f;
  unsigned u = x.u;
  u += 0x7fffu + ((u >> 16) & 1u);   // round-to-nearest-even
  return (unsigned short)(u >> 16);
}

// pack two f32 -> one u32 of two bf16 (RNE), single HW instr on gfx950
static __device__ __forceinline__ unsigned pk2(float lo, float hi) {
  unsigned r;
  asm("v_cvt_pk_bf16_f32 %0, %1, %2" : "=v"(r) : "v"(lo), "v"(hi));
  return r;
}

// ---------------------------------------------------------------- cast kernel
struct CastArgs {
  const float* src[8];
  unsigned short* dst[8];
  int n[8];
  float scl[8];
};

__global__ __launch_bounds__(256) void cast_all(CastArgs a) {
  int which = blockIdx.y;
  const float* __restrict__ src = a.src[which];
  unsigned short* __restrict__ dst = a.dst[which];
  int n = a.n[which];
  float s = a.scl[which];
  int i = (blockIdx.x * 256 + threadIdx.x) * 8;
  if (i >= n) return;
  f32x4 v0 = *(const f32x4*)(src + i);
  f32x4 v1 = *(const f32x4*)(src + i + 4);
  union { bf16x8 v; unsigned short u[8]; } o;
#pragma unroll
  for (int j = 0; j < 4; j++) { o.u[j] = f2bf(v0[j] * s); o.u[4 + j] = f2bf(v1[j] * s); }
  *(bf16x8*)(dst + i) = o.v;
}

// ---------------------------------------------------------------- GEMM body
// C[M=4096][N=1024] = A[4096][1024] @ B[1024][1024]^T   (A,B bf16, B is N x K)
// 128x128 tile, BK=32, 4 waves, each wave 64x64 (4x4 16x16 frags).
// mode 0: fp32 C[s][n] -> Cout
// mode 1: bf16 (h, s, d) head layout   (n = h*64+d)
// mode 2: bf16 (h, d, s) transposed    (for V)
static __device__ __forceinline__ void gemm_body(
    const unsigned short* __restrict__ A, const unsigned short* __restrict__ B,
    void* __restrict__ Cout, int mode, unsigned short* As, unsigned short* Bs) {
  const int K = 1024;
  int tid = threadIdx.x;
  int wid = tid >> 6, lane = tid & 63;
  int m0 = blockIdx.y * 128, n0 = blockIdx.x * 128;
  int wr = (wid >> 1) * 64, wc = (wid & 1) * 64;
  int g = lane >> 4, r = lane & 15;

  int lin = wid * 1024 + lane * 16;
  int row0 = lin >> 6;
  int el0 = (lin & 63) >> 1;
  const unsigned short* gA0 = A + (size_t)(m0 + row0) * K + el0;
  const unsigned short* gA1 = gA0 + (size_t)64 * K;
  const unsigned short* gB0 = B + (size_t)(n0 + row0) * K + el0;
  const unsigned short* gB1 = gB0 + (size_t)64 * K;
  unsigned short* lA = As + wid * 512;
  unsigned short* lB = Bs + wid * 512;

  f32x4 acc[4][4] = {};

  for (int k0 = 0; k0 < K; k0 += 32) {
    __builtin_amdgcn_global_load_lds(
        (const __attribute__((address_space(1))) void*)(gA0 + k0),
        (__attribute__((address_space(3))) void*)lA, 16, 0, 0);
    __builtin_amdgcn_global_load_lds(
        (const __attribute__((address_space(1))) void*)(gA1 + k0),
        (__attribute__((address_space(3))) void*)(lA + 2048), 16, 0, 0);
    __builtin_amdgcn_global_load_lds(
        (const __attribute__((address_space(1))) void*)(gB0 + k0),
        (__attribute__((address_space(3))) void*)lB, 16, 0, 0);
    __builtin_amdgcn_global_load_lds(
        (const __attribute__((address_space(1))) void*)(gB1 + k0),
        (__attribute__((address_space(3))) void*)(lB + 2048), 16, 0, 0);
    __syncthreads();

    bf16x8 af[4], bfr[4];
#pragma unroll
    for (int mi = 0; mi < 4; mi++)
      af[mi] = *(const bf16x8*)&As[(wr + mi * 16 + r) * 32 + g * 8];
#pragma unroll
    for (int ni = 0; ni < 4; ni++)
      bfr[ni] = *(const bf16x8*)&Bs[(wc + ni * 16 + r) * 32 + g * 8];
#pragma unroll
    for (int mi = 0; mi < 4; mi++)
#pragma unroll
      for (int ni = 0; ni < 4; ni++)
        acc[mi][ni] = __builtin_amdgcn_mfma_f32_16x16x32_bf16(
            af[mi], bfr[ni], acc[mi][ni], 0, 0, 0);
    __syncthreads();
  }

  if (mode == 0) {
    float* C = (float*)Cout;
#pragma unroll
    for (int mi = 0; mi < 4; mi++) {
      int row = m0 + wr + mi * 16 + g * 4;
#pragma unroll
      for (int ni = 0; ni < 4; ni++) {
        int c = n0 + wc + ni * 16 + r;
#pragma unroll
        for (int j = 0; j < 4; j++)
          C[(size_t)(row + j) * DM + c] = acc[mi][ni][j];
      }
    }
  } else if (mode == 1) {
    unsigned short* Cb = (unsigned short*)Cout;
#pragma unroll
    for (int mi = 0; mi < 4; mi++) {
      int row = m0 + wr + mi * 16 + g * 4;
#pragma unroll
      for (int ni = 0; ni < 4; ni++) {
        int c = n0 + wc + ni * 16 + r;
        int h = c >> 6, d = c & 63;
#pragma unroll
        for (int j = 0; j < 4; j++)
          Cb[(size_t)h * (S_LEN * DH) + (size_t)(row + j) * DH + d] =
              f2bf(acc[mi][ni][j]);
      }
    }
  } else {
    unsigned short* Cb = (unsigned short*)Cout;
#pragma unroll
    for (int mi = 0; mi < 4; mi++) {
      int row = m0 + wr + mi * 16 + g * 4;
#pragma unroll
      for (int ni = 0; ni < 4; ni++) {
        int c = n0 + wc + ni * 16 + r;
        int h = c >> 6, d = c & 63;
#pragma unroll
        for (int j = 0; j < 4; j++)
          Cb[(size_t)h * (S_LEN * DH) + (size_t)d * S_LEN + (row + j)] =
              f2bf(acc[mi][ni][j]);
      }
    }
  }
}

struct ProjArgs {
  const unsigned short* A[3];
  const unsigned short* B[3];
  unsigned short* C[3];
  int mode[3];
};

__global__ __launch_bounds__(256, 2) void gemm_proj(ProjArgs p) {
  __shared__ unsigned short As[4096];
  __shared__ unsigned short Bs[4096];
  int z = blockIdx.z;
  gemm_body(p.A[z], p.B[z], p.C[z], p.mode[z], As, Bs);
}

__global__ __launch_bounds__(256, 2) void gemm_one(
    const unsigned short* __restrict__ A, const unsigned short* __restrict__ B,
    void* __restrict__ Cout, int mode) {
  __shared__ unsigned short As[4096];
  __shared__ unsigned short Bs[4096];
  gemm_body(A, B, Cout, mode, As, Bs);
}

// ---------------------------------------------------------------- attention
// 512 blocks (32 q-supertiles x 16 heads), 256 thr = 4 waves x 32 q-rows.
// Swapped 32x32x16 MFMA: S^T = mfma(K, Q) -> P rows lane-local.
// K/V staged in XOR-swizzled double-buffered LDS (64 kv x 64 elem tiles).
// Causal balance: qe mapped so CU-paired blocks satisfy qe + qe' = 31.
__global__ __launch_bounds__(256, 2) void attn_fwd(
    const unsigned short* __restrict__ Qh, const unsigned short* __restrict__ Kh,
    const unsigned short* __restrict__ Vt, unsigned short* __restrict__ O) {
  __shared__ unsigned short Ks[2][64 * 64];   // [kv][d]  swizzled, 8KB each
  __shared__ unsigned short Vs[2][64 * 64];   // [d][kv]  swizzled, 8KB each

  const int b = blockIdx.x;
  const int hd = b & 15;
  const int t = b >> 4;                        // 0..31
  const int qe = (t < 16) ? (31 - 2 * t) : (2 * (t - 16));  // pairs sum to 31
  const int q0 = qe * 128;
  const int tid = threadIdx.x;
  const int wid = tid >> 6, lane = tid & 63;
  const int l31 = lane & 31, hi = lane >> 5;
  const int qw = q0 + wid * 32;
  const int qrow = qw + l31;

  const unsigned short* Qb = Qh + (size_t)hd * (S_LEN * DH);
  const unsigned short* Kb = Kh + (size_t)hd * (S_LEN * DH);
  const unsigned short* Vb = Vt + (size_t)hd * (S_LEN * DH);

  // Q fragments (B operand): col=q (l31), k = m*16 + hi*8 + j  (already /8 scaled)
  bf16x8 qf[4];
#pragma unroll
  for (int m = 0; m < 4; m++)
    qf[m] = *(const bf16x8*)&Qb[(size_t)qrow * DH + m * 16 + hi * 8];

  f32x16 oacc[2] = {};     // O^T: d = dt*32 + (reg&3)+8*(reg>>2)+4*hi, col q=l31
  float m_r = -1e30f, l_r = 0.f;

  // staging: thread covers rows srow, srow+32 of both 64x128B tiles
  const int srow = tid >> 3, scol = tid & 7;
  const int swz = (scol * 16) ^ ((srow & 7) << 4);
  const int wo0 = srow * 128 + swz;
  const int wo1 = (srow + 32) * 128 + swz;

  const int n_tiles = 2 * qe + 2;

  // prologue: stage tile 0 into buffer 0
  bf16x8 kp0 = *(const bf16x8*)&Kb[(size_t)srow * DH + scol * 8];
  bf16x8 kp1 = *(const bf16x8*)&Kb[(size_t)(srow + 32) * DH + scol * 8];
  bf16x8 vp0 = *(const bf16x8*)&Vb[(size_t)srow * S_LEN + scol * 8];
  bf16x8 vp1 = *(const bf16x8*)&Vb[(size_t)(srow + 32) * S_LEN + scol * 8];
  *(bf16x8*)((char*)Ks[0] + wo0) = kp0;
  *(bf16x8*)((char*)Ks[0] + wo1) = kp1;
  *(bf16x8*)((char*)Vs[0] + wo0) = vp0;
  *(bf16x8*)((char*)Vs[0] + wo1) = vp1;
  __syncthreads();

  int cur = 0;
  for (int it = 0; it < n_tiles; ++it) {
    const int kv0 = it * 64;
    const bool pre = (it + 1 < n_tiles);
    if (pre) {  // T14: issue next-tile global loads before compute
      const int kn = kv0 + 64;
      kp0 = *(const bf16x8*)&Kb[(size_t)(kn + srow) * DH + scol * 8];
      kp1 = *(const bf16x8*)&Kb[(size_t)(kn + srow + 32) * DH + scol * 8];
      vp0 = *(const bf16x8*)&Vb[(size_t)srow * S_LEN + kn + scol * 8];
      vp1 = *(const bf16x8*)&Vb[(size_t)(srow + 32) * S_LEN + kn + scol * 8];
    }
    const char* Kc = (const char*)Ks[cur];
    const char* Vc = (const char*)Vs[cur];
#pragma unroll
    for (int c = 0; c < 2; ++c) {
      const int kvc = kv0 + c * 32;
      if (kvc <= qw + 31) {            // wave-uniform causal skip
        // ---- QK^T (swapped): S^T[kv][q]
        f32x16 s = {};
#pragma unroll
        for (int m = 0; m < 4; m++) {
          bf16x8 kf = *(const bf16x8*)(Kc + (c * 32 + l31) * 128 +
                        ((m * 32 + hi * 16) ^ ((l31 & 7) << 4)));
          s = __builtin_amdgcn_mfma_f32_32x32x16_bf16(kf, qf[m], s, 0, 0, 0);
        }
        // ---- causal mask (reg -> kv: (reg&3) + 8*(reg>>2) + 4*hi)
        float x[16];
#pragma unroll
        for (int rg = 0; rg < 16; rg++) {
          int kvl = (rg & 3) + 8 * (rg >> 2) + 4 * hi;
          x[rg] = (kvc + kvl <= qrow) ? s[rg] : -1e30f;
        }
        // ---- online softmax: tree max/sum + single shfl_xor(32)
        float a0 = fmaxf(x[0], x[1]),  a1 = fmaxf(x[2], x[3]);
        float a2 = fmaxf(x[4], x[5]),  a3 = fmaxf(x[6], x[7]);
        float a4 = fmaxf(x[8], x[9]),  a5 = fmaxf(x[10], x[11]);
        float a6 = fmaxf(x[12], x[13]), a7 = fmaxf(x[14], x[15]);
        float b0 = fmaxf(a0, a1), b1 = fmaxf(a2, a3);
        float b2 = fmaxf(a4, a5), b3 = fmaxf(a6, a7);
        float mx = fmaxf(fmaxf(b0, b1), fmaxf(b2, b3));
        mx = fmaxf(mx, __shfl_xor(mx, 32, 64));
        float mnew = fmaxf(m_r, mx);
        float sc = __expf(m_r - mnew);
        m_r = mnew;
        float p[16];
#pragma unroll
        for (int rg = 0; rg < 16; rg++) p[rg] = __expf(x[rg] - mnew);
        float s0_ = (p[0] + p[1]) + (p[2] + p[3]);
        float s1_ = (p[4] + p[5]) + (p[6] + p[7]);
        float s2_ = (p[8] + p[9]) + (p[10] + p[11]);
        float s3_ = (p[12] + p[13]) + (p[14] + p[15]);
        float rs = (s0_ + s1_) + (s2_ + s3_);
        rs += __shfl_xor(rs, 32, 64);
        l_r = l_r * sc + rs;
#pragma unroll
        for (int dt = 0; dt < 2; dt++)
#pragma unroll
          for (int rg = 0; rg < 16; rg++) oacc[dt][rg] *= sc;
        // ---- P -> bf16 in-register + cross-half exchange (T12)
        uint2 pk[4], pp[4];
#pragma unroll
        for (int blk = 0; blk < 4; blk++) {
          pk[blk].x = pk2(p[blk * 4 + 0], p[blk * 4 + 1]);
          pk[blk].y = pk2(p[blk * 4 + 2], p[blk * 4 + 3]);
          pp[blk].x = (unsigned)__shfl_xor((int)pk[blk].x, 32, 64);
          pp[blk].y = (unsigned)__shfl_xor((int)pk[blk].y, 32, 64);
        }
        // B-frag n: k = kv n*16 + hi*8 + j  (own half + partner half)
        bf16x8 bfrag[2];
#pragma unroll
        for (int n = 0; n < 2; n++) {
          union { unsigned w[4]; bf16x8 v; } u;
          u.w[0] = hi ? pp[2 * n + 1].x : pk[2 * n].x;
          u.w[1] = hi ? pp[2 * n + 1].y : pk[2 * n].y;
          u.w[2] = hi ? pk[2 * n + 1].x : pp[2 * n].x;
          u.w[3] = hi ? pk[2 * n + 1].y : pp[2 * n].y;
          bfrag[n] = u.v;
        }
        // ---- PV: O^T += V^T x P
#pragma unroll
        for (int dt = 0; dt < 2; dt++)
#pragma unroll
          for (int n = 0; n < 2; n++) {
            bf16x8 vf = *(const bf16x8*)(Vc + (dt * 32 + l31) * 128 +
                          ((c * 64 + n * 32 + hi * 16) ^ ((l31 & 7) << 4)));
            oacc[dt] = __builtin_amdgcn_mfma_f32_32x32x16_bf16(
                vf, bfrag[n], oacc[dt], 0, 0, 0);
          }
      }
    }
    if (pre) {   // write prefetched tile into alternate buffer
      char* Kn = (char*)Ks[cur ^ 1];
      char* Vn = (char*)Vs[cur ^ 1];
      *(bf16x8*)(Kn + wo0) = kp0;
      *(bf16x8*)(Kn + wo1) = kp1;
      *(bf16x8*)(Vn + wo0) = vp0;
      *(bf16x8*)(Vn + wo1) = vp1;
    }
    __syncthreads();
    cur ^= 1;
  }

  // epilogue: O[q][h*64+d] = oacc/l, packed 4-bf16 stores
  float rl = 1.0f / l_r;
#pragma unroll
  for (int dt = 0; dt < 2; dt++)
#pragma unroll
    for (int blk = 0; blk < 4; blk++) {
      unsigned w0 = pk2(oacc[dt][blk * 4 + 0] * rl, oacc[dt][blk * 4 + 1] * rl);
      unsigned w1 = pk2(oacc[dt][blk * 4 + 2] * rl, oacc[dt][blk * 4 + 3] * rl);
      int d0 = dt * 32 + blk * 8 + 4 * hi;
      uint2 st; st.x = w0; st.y = w1;
      *(uint2*)&O[(size_t)qrow * DM + hd * DH + d0] = st;
    }
}

// ---------------------------------------------------------------- launch
extern "C" void kernel_launch(void* const* d_in, const int* in_sizes, int n_in,
                              void* d_out, int out_size, void* d_ws, size_t ws_size,
                              hipStream_t stream) {
  const float* q = (const float*)d_in[0];
  const float* k = (const float*)d_in[1];
  const float* v = (const float*)d_in[2];
  // d_in[3] = mask (causal, reconstructed analytically)
  const float* Wq = (const float*)d_in[4];
  const float* Wk = (const float*)d_in[5];
  const float* Wv = (const float*)d_in[6];
  const float* Wo = (const float*)d_in[7];

  unsigned short* W = (unsigned short*)d_ws;
  const int SM = S_LEN * DM;        // 4194304
  const int WM = DM * DM;           // 1048576
  unsigned short* qb  = W;
  unsigned short* kb  = qb + SM;
  unsigned short* vb  = kb + SM;
  unsigned short* Wqb = vb + SM;
  unsigned short* Wkb = Wqb + WM;
  unsigned short* Wvb = Wkb + WM;
  unsigned short* Wob = Wvb + WM;
  unsigned short* Qh  = Wob + WM;
  unsigned short* Kh  = Qh + SM;
  unsigned short* Vt  = Kh + SM;
  unsigned short* Ob  = Vt + SM;

  // 1) casts (fused, 8 arrays); Wq carries the 1/sqrt(64) attention scale
  CastArgs ca;
  ca.src[0] = q;  ca.dst[0] = qb;  ca.n[0] = SM; ca.scl[0] = 1.f;
  ca.src[1] = k;  ca.dst[1] = kb;  ca.n[1] = SM; ca.scl[1] = 1.f;
  ca.src[2] = v;  ca.dst[2] = vb;  ca.n[2] = SM; ca.scl[2] = 1.f;
  ca.src[3] = Wq; ca.dst[3] = Wqb; ca.n[3] = WM; ca.scl[3] = 0.125f;
  ca.src[4] = Wk; ca.dst[4] = Wkb; ca.n[4] = WM; ca.scl[4] = 1.f;
  ca.src[5] = Wv; ca.dst[5] = Wvb; ca.n[5] = WM; ca.scl[5] = 1.f;
  ca.src[6] = Wo; ca.dst[6] = Wob; ca.n[6] = WM; ca.scl[6] = 1.f;
  ca.src[7] = Wo; ca.dst[7] = Wob; ca.n[7] = 0;  ca.scl[7] = 1.f;
  cast_all<<<dim3(2048, 8), 256, 0, stream>>>(ca);

  // 2) batched projections
  ProjArgs pa;
  pa.A[0] = qb; pa.B[0] = Wqb; pa.C[0] = Qh; pa.mode[0] = 1;
  pa.A[1] = kb; pa.B[1] = Wkb; pa.C[1] = Kh; pa.mode[1] = 1;
  pa.A[2] = vb; pa.B[2] = Wvb; pa.C[2] = Vt; pa.mode[2] = 2;
  gemm_proj<<<dim3(8, 32, 3), 256, 0, stream>>>(pa);

  // 3) causal flash attention (swapped 32x32 MFMA)
  attn_fwd<<<dim3(512), 256, 0, stream>>>(Qh, Kh, Vt, Ob);

  // 4) output projection -> fp32
  gemm_one<<<dim3(8, 32), 256, 0, stream>>>(Ob, Wob, d_out, 0);
}

// Round 4
// 142.580 us; speedup vs baseline: 2.8326x; 1.3704x over previous
//
#include <hip/hip_runtime.h>

// ---------------------------------------------------------------------------
// MultiHeadAttention forward, MI355X (gfx950), bf16 MFMA pipeline.
// Round 4 = round 3 structure with all cross-lane ops reverted to the
// round-2-proven __shfl_xor(32) pattern (permlane32_swap asm removed — prime
// suspect for the round-3 numerical failure).
//   - kv-split x2 within block: 8 waves (4 q-waves x 2 kv-halves), LDS combine
//   - one softmax pass per 64-kv tile; defer-max; exp2 domain
//   - diagonal-only causal masking (wave-uniform interior fast path)
//   - K/V staged via global_load_lds (pre-swizzled global src, linear LDS),
//     double-buffered
// ---------------------------------------------------------------------------

typedef __attribute__((ext_vector_type(8))) short bf16x8;
typedef __attribute__((ext_vector_type(4))) float f32x4;
typedef __attribute__((ext_vector_type(16))) float f32x16;

#define S_LEN 4096
#define DM 1024
#define NH 16
#define DH 64

static __device__ __forceinline__ unsigned short f2bf(float f) {
  union { float f; unsigned u; } x; x.f = f;
  unsigned u = x.u;
  u += 0x7fffu + ((u >> 16) & 1u);   // round-to-nearest-even
  return (unsigned short)(u >> 16);
}

// pack two f32 -> one u32 of two bf16 (RNE), single HW instr on gfx950
static __device__ __forceinline__ unsigned pk2(float lo, float hi) {
  unsigned r;
  asm("v_cvt_pk_bf16_f32 %0, %1, %2" : "=v"(r) : "v"(lo), "v"(hi));
  return r;
}

static __device__ __forceinline__ float exp2_(float x) {
#if __has_builtin(__builtin_amdgcn_exp2f)
  return __builtin_amdgcn_exp2f(x);
#else
  return exp2f(x);
#endif
}

#define GLL16(gsrc, ldst)                                                      \
  __builtin_amdgcn_global_load_lds(                                            \
      (const __attribute__((address_space(1))) void*)(gsrc),                   \
      (__attribute__((address_space(3))) void*)(ldst), 16, 0, 0)

// ---------------------------------------------------------------- cast kernel
struct CastArgs {
  const float* src[8];
  unsigned short* dst[8];
  int n[8];
  float scl[8];
};

__global__ __launch_bounds__(256) void cast_all(CastArgs a) {
  int which = blockIdx.y;
  const float* __restrict__ src = a.src[which];
  unsigned short* __restrict__ dst = a.dst[which];
  int n = a.n[which];
  float s = a.scl[which];
  int i = (blockIdx.x * 256 + threadIdx.x) * 8;
  if (i >= n) return;
  f32x4 v0 = *(const f32x4*)(src + i);
  f32x4 v1 = *(const f32x4*)(src + i + 4);
  union { bf16x8 v; unsigned short u[8]; } o;
#pragma unroll
  for (int j = 0; j < 4; j++) { o.u[j] = f2bf(v0[j] * s); o.u[4 + j] = f2bf(v1[j] * s); }
  *(bf16x8*)(dst + i) = o.v;
}

// ---------------------------------------------------------------- GEMM body
// (unchanged from round 2 -- verified correct)
static __device__ __forceinline__ void gemm_body(
    const unsigned short* __restrict__ A, const unsigned short* __restrict__ B,
    void* __restrict__ Cout, int mode, unsigned short* As, unsigned short* Bs) {
  const int K = 1024;
  int tid = threadIdx.x;
  int wid = tid >> 6, lane = tid & 63;
  int m0 = blockIdx.y * 128, n0 = blockIdx.x * 128;
  int wr = (wid >> 1) * 64, wc = (wid & 1) * 64;
  int g = lane >> 4, r = lane & 15;

  int lin = wid * 1024 + lane * 16;
  int row0 = lin >> 6;
  int el0 = (lin & 63) >> 1;
  const unsigned short* gA0 = A + (size_t)(m0 + row0) * K + el0;
  const unsigned short* gA1 = gA0 + (size_t)64 * K;
  const unsigned short* gB0 = B + (size_t)(n0 + row0) * K + el0;
  const unsigned short* gB1 = gB0 + (size_t)64 * K;
  unsigned short* lA = As + wid * 512;
  unsigned short* lB = Bs + wid * 512;

  f32x4 acc[4][4] = {};

  for (int k0 = 0; k0 < K; k0 += 32) {
    GLL16(gA0 + k0, lA);
    GLL16(gA1 + k0, lA + 2048);
    GLL16(gB0 + k0, lB);
    GLL16(gB1 + k0, lB + 2048);
    __syncthreads();

    bf16x8 af[4], bfr[4];
#pragma unroll
    for (int mi = 0; mi < 4; mi++)
      af[mi] = *(const bf16x8*)&As[(wr + mi * 16 + r) * 32 + g * 8];
#pragma unroll
    for (int ni = 0; ni < 4; ni++)
      bfr[ni] = *(const bf16x8*)&Bs[(wc + ni * 16 + r) * 32 + g * 8];
#pragma unroll
    for (int mi = 0; mi < 4; mi++)
#pragma unroll
      for (int ni = 0; ni < 4; ni++)
        acc[mi][ni] = __builtin_amdgcn_mfma_f32_16x16x32_bf16(
            af[mi], bfr[ni], acc[mi][ni], 0, 0, 0);
    __syncthreads();
  }

  if (mode == 0) {
    float* C = (float*)Cout;
#pragma unroll
    for (int mi = 0; mi < 4; mi++) {
      int row = m0 + wr + mi * 16 + g * 4;
#pragma unroll
      for (int ni = 0; ni < 4; ni++) {
        int c = n0 + wc + ni * 16 + r;
#pragma unroll
        for (int j = 0; j < 4; j++)
          C[(size_t)(row + j) * DM + c] = acc[mi][ni][j];
      }
    }
  } else if (mode == 1) {
    unsigned short* Cb = (unsigned short*)Cout;
#pragma unroll
    for (int mi = 0; mi < 4; mi++) {
      int row = m0 + wr + mi * 16 + g * 4;
#pragma unroll
      for (int ni = 0; ni < 4; ni++) {
        int c = n0 + wc + ni * 16 + r;
        int h = c >> 6, d = c & 63;
#pragma unroll
        for (int j = 0; j < 4; j++)
          Cb[(size_t)h * (S_LEN * DH) + (size_t)(row + j) * DH + d] =
              f2bf(acc[mi][ni][j]);
      }
    }
  } else {
    unsigned short* Cb = (unsigned short*)Cout;
#pragma unroll
    for (int mi = 0; mi < 4; mi++) {
      int row = m0 + wr + mi * 16 + g * 4;
#pragma unroll
      for (int ni = 0; ni < 4; ni++) {
        int c = n0 + wc + ni * 16 + r;
        int h = c >> 6, d = c & 63;
#pragma unroll
        for (int j = 0; j < 4; j++)
          Cb[(size_t)h * (S_LEN * DH) + (size_t)d * S_LEN + (row + j)] =
              f2bf(acc[mi][ni][j]);
      }
    }
  }
}

struct ProjArgs {
  const unsigned short* A[3];
  const unsigned short* B[3];
  unsigned short* C[3];
  int mode[3];
};

__global__ __launch_bounds__(256, 2) void gemm_proj(ProjArgs p) {
  __shared__ unsigned short As[4096];
  __shared__ unsigned short Bs[4096];
  int z = blockIdx.z;
  gemm_body(p.A[z], p.B[z], p.C[z], p.mode[z], As, Bs);
}

__global__ __launch_bounds__(256, 2) void gemm_one(
    const unsigned short* __restrict__ A, const unsigned short* __restrict__ B,
    void* __restrict__ Cout, int mode) {
  __shared__ unsigned short As[4096];
  __shared__ unsigned short Bs[4096];
  gemm_body(A, B, Cout, mode, As, Bs);
}

// ---------------------------------------------------------------- attention
// 512 blocks (32 q-supertiles x 16 heads) x 512 threads (8 waves).
// wave = (gg = kv-half, qi = q-sub-block): q rows [q0+qi*32, +32),
// kv tiles [gg*nt*64, (gg+1)*nt*64) in 64-kv steps, nt = qe+1.
// End: halves combined via LDS (m, l, O merge), gg=0 waves store O.
__global__ __launch_bounds__(512, 4) void attn_fwd(
    const unsigned short* __restrict__ Qh, const unsigned short* __restrict__ Kh,
    const unsigned short* __restrict__ Vt, unsigned short* __restrict__ O) {
  __shared__ char smem[65536];   // [gg][db] 16KB chunks {K 8KB, V 8KB}; reused as combine scratch

  const int b = blockIdx.x;
  const int hd = b & 15;
  const int t = b >> 4;
  const int qe = (t < 16) ? (31 - 2 * t) : (2 * (t - 16));  // CU-pairs sum to 31
  const int q0 = qe * 128;
  const int nt = qe + 1;

  const int tid = threadIdx.x;
  const int gg = tid >> 8;            // kv half
  const int ww = (tid >> 6) & 3;      // wave within half-group
  const int lane = tid & 63;
  const int l31 = lane & 31, hi = lane >> 5;
  const int qi = ww;
  const int qw = q0 + qi * 32;
  const int qrow = qw + l31;
  const int sw = (l31 & 7) << 4;

  const unsigned short* Qb = Qh + (size_t)hd * (S_LEN * DH);
  const char* Kb = (const char*)(Kh + (size_t)hd * (S_LEN * DH));
  const char* Vb = (const char*)(Vt + (size_t)hd * (S_LEN * DH));

  // Q fragments (B operand): col = q (l31), k = m*16 + hi*8 + j (pre-scaled)
  bf16x8 qf[4];
#pragma unroll
  for (int m = 0; m < 4; m++)
    qf[m] = *(const bf16x8*)&Qb[(size_t)qrow * DH + m * 16 + hi * 8];

  // ---- staging geometry: waves 0-1 of each group stage K, 2-3 stage V.
  // LDS is linear; swizzle achieved by pre-swizzling the GLOBAL source addr.
  const int roleV = (ww >= 2);
  const int wv = ww & 1;
  const char* gb = roleV ? Vb : Kb;
  const long tstep = roleV ? 128 : 8192;   // bytes per 64-kv tile step
  int soff[4];
#pragma unroll
  for (int q2 = 0; q2 < 4; q2++) {
    int rowl = wv * 32 + q2 * 8 + (lane >> 3);
    int cb = ((lane & 7) * 16) ^ (((lane >> 3) & 7) << 4);
    soff[q2] = roleV ? (rowl * 8192 + cb) : (rowl * 128 + cb);
  }
  const int ldsc = gg * 32768 + roleV * 8192 + wv * 4096;  // + db*16384

  f32x16 oacc[2] = {};    // O^T: d = dt*32 + (rg&3)+8*(rg>>2)+4*hi, col q = l31
  float m_r = -1e30f, l_r = 0.f;

  // prologue: stage this group's tile 0 into db=0
  {
    const char* gp = gb + (long)(gg * nt) * tstep;
#pragma unroll
    for (int q2 = 0; q2 < 4; q2++)
      GLL16(gp + soff[q2], smem + ldsc + q2 * 1024);
  }
  __syncthreads();

  int db = 0;
  for (int it = 0; it < nt; ++it) {
    if (it + 1 < nt) {   // prefetch next tile into alternate buffer (async)
      const char* gp = gb + (long)(gg * nt + it + 1) * tstep;
      char* lb = smem + ldsc + (db ^ 1) * 16384;
#pragma unroll
      for (int q2 = 0; q2 < 4; q2++)
        GLL16(gp + soff[q2], lb + q2 * 1024);
    }
    const int kv0 = (gg * nt + it) * 64;
    const char* Kc = smem + gg * 32768 + db * 16384;
    const char* Vc = Kc + 8192;

    if (kv0 <= qw + 31) {                       // wave-uniform causal skip
      const bool hiP = (kv0 + 32 <= qw + 31);   // upper 32-kv sub-tile present
      const bool interior = (kv0 + 63 <= qw);   // no masking anywhere
      // ---- QK^T (swapped): S^T[kv][q], log2 domain
      f32x16 s0 = {}, s1 = {};
#pragma unroll
      for (int m = 0; m < 4; m++) {
        bf16x8 kf = *(const bf16x8*)(Kc + l31 * 128 + ((m * 32 + hi * 16) ^ sw));
        s0 = __builtin_amdgcn_mfma_f32_32x32x16_bf16(kf, qf[m], s0, 0, 0, 0);
      }
      if (hiP) {
#pragma unroll
        for (int m = 0; m < 4; m++) {
          bf16x8 kf = *(const bf16x8*)(Kc + (32 + l31) * 128 + ((m * 32 + hi * 16) ^ sw));
          s1 = __builtin_amdgcn_mfma_f32_32x32x16_bf16(kf, qf[m], s1, 0, 0, 0);
        }
      }
      // ---- causal mask: diagonal tiles only (reg -> kv: (rg&3)+8*(rg>>2)+4*hi)
      if (!interior) {
#pragma unroll
        for (int rg = 0; rg < 16; rg++) {
          const int kvl = (rg & 3) + 8 * (rg >> 2) + 4 * hi;
          s0[rg] = (kv0 + kvl <= qrow) ? s0[rg] : -1e30f;
          s1[rg] = (hiP && kv0 + 32 + kvl <= qrow) ? s1[rg] : -1e30f;
        }
      }
      // ---- max: in-lane tree + shfl_xor(32) cross-half (round-2-proven)
      float a0 = fmaxf(s0[0], s0[1]),  a1 = fmaxf(s0[2], s0[3]);
      float a2 = fmaxf(s0[4], s0[5]),  a3 = fmaxf(s0[6], s0[7]);
      float a4 = fmaxf(s0[8], s0[9]),  a5 = fmaxf(s0[10], s0[11]);
      float a6 = fmaxf(s0[12], s0[13]), a7 = fmaxf(s0[14], s0[15]);
      float b0 = fmaxf(s1[0], s1[1]),  b1 = fmaxf(s1[2], s1[3]);
      float b2 = fmaxf(s1[4], s1[5]),  b3 = fmaxf(s1[6], s1[7]);
      float b4 = fmaxf(s1[8], s1[9]),  b5 = fmaxf(s1[10], s1[11]);
      float b6 = fmaxf(s1[12], s1[13]), b7 = fmaxf(s1[14], s1[15]);
      float c0 = fmaxf(fmaxf(a0, a1), fmaxf(a2, a3));
      float c1 = fmaxf(fmaxf(a4, a5), fmaxf(a6, a7));
      float c2 = fmaxf(fmaxf(b0, b1), fmaxf(b2, b3));
      float c3 = fmaxf(fmaxf(b4, b5), fmaxf(b6, b7));
      float mx = fmaxf(fmaxf(c0, c1), fmaxf(c2, c3));
      mx = fmaxf(mx, __shfl_xor(mx, 32, 64));
      // ---- defer-max (T13): rescale only when max grew past THR
      if (__any(mx > m_r + 10.0f)) {
        float mnew = fmaxf(m_r, mx);
        float sc = exp2_(m_r - mnew);
        m_r = mnew;
        l_r *= sc;
#pragma unroll
        for (int dt = 0; dt < 2; dt++)
#pragma unroll
          for (int rg = 0; rg < 16; rg++) oacc[dt][rg] *= sc;
      }
      // ---- P = exp2(S - m) in place
#pragma unroll
      for (int rg = 0; rg < 16; rg++) {
        s0[rg] = exp2_(s0[rg] - m_r);
        s1[rg] = exp2_(s1[rg] - m_r);
      }
      // ---- row-sum (parallel quads) + shfl_xor(32) cross-half
      float r0 = (s0[0] + s0[1]) + (s0[2] + s0[3]);
      float r1 = (s0[4] + s0[5]) + (s0[6] + s0[7]);
      float r2 = (s0[8] + s0[9]) + (s0[10] + s0[11]);
      float r3 = (s0[12] + s0[13]) + (s0[14] + s0[15]);
      float r4 = (s1[0] + s1[1]) + (s1[2] + s1[3]);
      float r5 = (s1[4] + s1[5]) + (s1[6] + s1[7]);
      float r6 = (s1[8] + s1[9]) + (s1[10] + s1[11]);
      float r7 = (s1[12] + s1[13]) + (s1[14] + s1[15]);
      float rs = ((r0 + r1) + (r2 + r3)) + ((r4 + r5) + (r6 + r7));
      rs += __shfl_xor(rs, 32, 64);
      l_r += rs;
      // ---- P -> bf16 frags via cvt_pk + shfl_xor(32) (round-2-proven select)
#pragma unroll
      for (int c = 0; c < 2; c++) {
        if (c == 0 || hiP) {
          const f32x16 P = c ? s1 : s0;
          uint2 pk[4], pp[4];
#pragma unroll
          for (int blk = 0; blk < 4; blk++) {
            pk[blk].x = pk2(P[blk * 4 + 0], P[blk * 4 + 1]);
            pk[blk].y = pk2(P[blk * 4 + 2], P[blk * 4 + 3]);
            pp[blk].x = (unsigned)__shfl_xor((int)pk[blk].x, 32, 64);
            pp[blk].y = (unsigned)__shfl_xor((int)pk[blk].y, 32, 64);
          }
#pragma unroll
          for (int n = 0; n < 2; n++) {
            union { unsigned w[4]; bf16x8 v; } u;
            u.w[0] = hi ? pp[2 * n + 1].x : pk[2 * n].x;
            u.w[1] = hi ? pp[2 * n + 1].y : pk[2 * n].y;
            u.w[2] = hi ? pk[2 * n + 1].x : pp[2 * n].x;
            u.w[3] = hi ? pk[2 * n + 1].y : pp[2 * n].y;
#pragma unroll
            for (int dt = 0; dt < 2; dt++) {
              bf16x8 vf = *(const bf16x8*)(Vc + (dt * 32 + l31) * 128 +
                            ((c * 64 + n * 32 + hi * 16) ^ sw));
              oacc[dt] = __builtin_amdgcn_mfma_f32_32x32x16_bf16(
                  vf, u.v, oacc[dt], 0, 0, 0);
            }
          }
        }
      }
    }
    __syncthreads();
    db ^= 1;
  }

  // ---- combine halves via LDS scratch (stride 35 floats: conflict-free)
  float* scr = (float*)smem;
  const int sbase = (qi * 64 + lane) * 35;
  if (gg == 1) {
#pragma unroll
    for (int dt = 0; dt < 2; dt++)
#pragma unroll
      for (int rg = 0; rg < 16; rg++) scr[sbase + dt * 16 + rg] = oacc[dt][rg];
    scr[sbase + 32] = m_r;
    scr[sbase + 33] = l_r;
  }
  __syncthreads();
  if (gg == 0) {
    float mB = scr[sbase + 32], lB = scr[sbase + 33];
    float mS = fmaxf(m_r, mB);
    float sA = exp2_(m_r - mS);
    float sB = exp2_(mB - mS);
    float rl = 1.0f / (l_r * sA + lB * sB);
    float fA = sA * rl, fB = sB * rl;
#pragma unroll
    for (int dt = 0; dt < 2; dt++)
#pragma unroll
      for (int blk = 0; blk < 4; blk++) {
        float v0 = oacc[dt][blk * 4 + 0] * fA + scr[sbase + dt * 16 + blk * 4 + 0] * fB;
        float v1 = oacc[dt][blk * 4 + 1] * fA + scr[sbase + dt * 16 + blk * 4 + 1] * fB;
        float v2 = oacc[dt][blk * 4 + 2] * fA + scr[sbase + dt * 16 + blk * 4 + 2] * fB;
        float v3 = oacc[dt][blk * 4 + 3] * fA + scr[sbase + dt * 16 + blk * 4 + 3] * fB;
        uint2 st; st.x = pk2(v0, v1); st.y = pk2(v2, v3);
        int d0 = dt * 32 + blk * 8 + 4 * hi;
        *(uint2*)&O[(size_t)qrow * DM + hd * DH + d0] = st;
      }
  }
}

// ---------------------------------------------------------------- launch
extern "C" void kernel_launch(void* const* d_in, const int* in_sizes, int n_in,
                              void* d_out, int out_size, void* d_ws, size_t ws_size,
                              hipStream_t stream) {
  const float* q = (const float*)d_in[0];
  const float* k = (const float*)d_in[1];
  const float* v = (const float*)d_in[2];
  // d_in[3] = mask (causal, reconstructed analytically)
  const float* Wq = (const float*)d_in[4];
  const float* Wk = (const float*)d_in[5];
  const float* Wv = (const float*)d_in[6];
  const float* Wo = (const float*)d_in[7];

  unsigned short* W = (unsigned short*)d_ws;
  const int SM = S_LEN * DM;        // 4194304
  const int WM = DM * DM;           // 1048576
  unsigned short* qb  = W;
  unsigned short* kb  = qb + SM;
  unsigned short* vb  = kb + SM;
  unsigned short* Wqb = vb + SM;
  unsigned short* Wkb = Wqb + WM;
  unsigned short* Wvb = Wkb + WM;
  unsigned short* Wob = Wvb + WM;
  unsigned short* Qh  = Wob + WM;
  unsigned short* Kh  = Qh + SM;
  unsigned short* Vt  = Kh + SM;
  unsigned short* Ob  = Vt + SM;

  // 1) casts; Wq carries attention scale in log2 domain: 0.125 * log2(e)
  CastArgs ca;
  ca.src[0] = q;  ca.dst[0] = qb;  ca.n[0] = SM; ca.scl[0] = 1.f;
  ca.src[1] = k;  ca.dst[1] = kb;  ca.n[1] = SM; ca.scl[1] = 1.f;
  ca.src[2] = v;  ca.dst[2] = vb;  ca.n[2] = SM; ca.scl[2] = 1.f;
  ca.src[3] = Wq; ca.dst[3] = Wqb; ca.n[3] = WM; ca.scl[3] = 0.125f * 1.44269504f;
  ca.src[4] = Wk; ca.dst[4] = Wkb; ca.n[4] = WM; ca.scl[4] = 1.f;
  ca.src[5] = Wv; ca.dst[5] = Wvb; ca.n[5] = WM; ca.scl[5] = 1.f;
  ca.src[6] = Wo; ca.dst[6] = Wob; ca.n[6] = WM; ca.scl[6] = 1.f;
  ca.src[7] = Wo; ca.dst[7] = Wob; ca.n[7] = 0;  ca.scl[7] = 1.f;
  cast_all<<<dim3(2048, 8), 256, 0, stream>>>(ca);

  // 2) batched projections: Q->(h,s,d), K->(h,s,d), V->(h,d,s)
  ProjArgs pa;
  pa.A[0] = qb; pa.B[0] = Wqb; pa.C[0] = Qh; pa.mode[0] = 1;
  pa.A[1] = kb; pa.B[1] = Wkb; pa.C[1] = Kh; pa.mode[1] = 1;
  pa.A[2] = vb; pa.B[2] = Wvb; pa.C[2] = Vt; pa.mode[2] = 2;
  gemm_proj<<<dim3(8, 32, 3), 256, 0, stream>>>(pa);

  // 3) causal flash attention (kv-split x2, 8 waves/block)
  attn_fwd<<<dim3(512), 512, 0, stream>>>(Qh, Kh, Vt, Ob);

  // 4) output projection -> fp32
  gemm_one<<<dim3(8, 32), 256, 0, stream>>>(Ob, Wob, d_out, 0);
}